// Round 10
// baseline (317.481 us; speedup 1.0000x reference)
//
#include <hip/hip_runtime.h>

typedef unsigned short u16;
typedef unsigned int u32;
typedef __attribute__((ext_vector_type(8))) short bf16x8;
typedef __attribute__((ext_vector_type(4))) float f32x4;

#define EPSBN 0.001f
#define MFMA16(a, b, c) __builtin_amdgcn_mfma_f32_16x16x32_bf16(a, b, c, 0, 0, 0)

__device__ __forceinline__ float bf2f(u16 u) {
    return __uint_as_float(((u32)u) << 16);
}
__device__ __forceinline__ u16 f2bf(float f) {
    u32 u = __float_as_uint(f);
    u32 r = u + 0x7FFFu + ((u >> 16) & 1u);
    return (u16)(r >> 16);
}
__device__ __forceinline__ float relu(float x) { return x > 0.f ? x : 0.f; }
__device__ __forceinline__ float rdv(const void* p, int i, int isbf) {
    return isbf ? bf2f(((const u16*)p)[i]) : ((const float*)p)[i];
}

// ---------------- ws layout (float offsets) ----------------
// [0]: flag u32
#define A_INPUTS 64       // 196608
#define A_TC1W  196672
#define A_TC1B  196864
#define A_TBN1  196928
#define A_TD1W  197184
#define A_TD1B  201280
#define A_TBN2  201344
#define A_TD2W  201600
#define A_TD2B  202176
#define A_BN3   249216
#define A_D1W   250240
#define A_D1B   251008
#define A_BNGF  420928
#define S_PCT   423808    // 196608 (32*2048*3 f32)
// zeroed region: [S_MAXF, S_MAXF+12288)
#define S_MAXF  620544    // 8192 u32 (maxfeats)
#define S_NETMAX 628736   // 4096 u32
// bf16 transposed+scaled weight arenas
#define T_C1WT  634880    // 128x96  u16
#define T_C2WT  641024    // 256x128 u16
#define T_W4T   657408    // 256x512 u16
#define T_W5T   722944    // 128x256 u16
// folded small params (f32)
#define P_W3S   739328    // 1536
#define P_B3S   740864    // 512
#define P_BP1   741376    // 128
#define P_BP2   741504    // 256
#define P_BP4   741760    // 256
#define P_BP5   742016    // 128
// end 742144 floats = 2.97 MB

struct SmallCv { const void* src[12]; int n[12]; int off[12]; };
struct PrepWA { const void* src[4]; const void* bn[4]; int K[4]; int logN[4]; int base[4]; int dstoff[4]; };
struct PrepSm { const void *bn4, *c3w, *c3b, *bn2, *c2b, *blk1bn, *blk1b, *bn1, *c1b, *blk2bn, *blk2b; };

// ================= K0: prep everything (140 blocks) =================
// blocks 0..31: inputs convert; 32..35: small tensors; 36..137: weight tile-transpose;
// 138: folded params; 139: zero-init + flag
__global__ __launch_bounds__(256) void k_prep(SmallCv sc, PrepWA pw, PrepSm ps,
                                              const void* __restrict__ inputs_raw,
                                              const u16* __restrict__ tbn1_raw,
                                              float* __restrict__ ws) {
    __shared__ float tile[32][65];
    __shared__ float scol[64];
    int isbf = 1;
    for (int i = 0; i < 16; i += 2) {
        u16 v = tbn1_raw[i];
        if (v < 0x3E00u || v > 0x4080u) isbf = 0;
    }
    int bx = blockIdx.x, tid = threadIdx.x;
    if (bx < 32) {
        float* dst = ws + A_INPUTS;
        for (int i = bx * 256 + tid; i < 196608; i += 8192) dst[i] = rdv(inputs_raw, i, isbf);
    } else if (bx < 36) {
        int t0 = (bx - 32) * 3;
        for (int t = t0; t < t0 + 3; t++) {
            int n = sc.n[t];
            float* dst = ws + sc.off[t];
            for (int i = tid; i < n; i += 256) dst[i] = rdv(sc.src[t], i, isbf);
        }
    } else if (bx < 138) {
        int blk = bx - 36;
        int t = (blk < 6) ? 0 : (blk < 22) ? 1 : (blk < 86) ? 2 : 3;
        int tt = blk - pw.base[t];
        int N = 1 << pw.logN[t];
        int K = pw.K[t];
        int ct = N >> 6;
        int k0 = (tt / ct) * 32, c0 = (tt % ct) * 64;
        if (tid < 64) {
            int c = c0 + tid;
            scol[tid] = rdv(pw.bn[t], c, isbf) * rsqrtf(rdv(pw.bn[t], 3 * N + c, isbf) + EPSBN);
        }
        __syncthreads();
#pragma unroll
        for (int pr = 0; pr < 8; pr++) {
            int kr = pr * 4 + (tid >> 6), cc = tid & 63;
            tile[kr][cc] = rdv(pw.src[t], (k0 + kr) * N + c0 + cc, isbf) * scol[cc];
        }
        __syncthreads();
        u32* d32 = (u32*)((u16*)(ws + pw.dstoff[t]));
#pragma unroll
        for (int pw2 = 0; pw2 < 4; pw2++) {
            int cr = pw2 * 16 + (tid >> 4);
            int kp = tid & 15;
            u32 pk = (u32)f2bf(tile[kp * 2][cr]) | ((u32)f2bf(tile[kp * 2 + 1][cr]) << 16);
            d32[(((c0 + cr) * K + k0) >> 1) + kp] = pk;
        }
    } else if (bx == 138) {
        for (int c = tid; c < 512; c += 256) {
            float s = rdv(ps.bn4, c, isbf) * rsqrtf(rdv(ps.bn4, 1536 + c, isbf) + EPSBN);
            float t = rdv(ps.bn4, 512 + c, isbf) - rdv(ps.bn4, 1024 + c, isbf) * s;
            ws[P_W3S + c]        = rdv(ps.c3w, c, isbf) * s;
            ws[P_W3S + 512 + c]  = rdv(ps.c3w, 512 + c, isbf) * s;
            ws[P_W3S + 1024 + c] = rdv(ps.c3w, 1024 + c, isbf) * s;
            ws[P_B3S + c] = rdv(ps.c3b, c, isbf) * s + t;
        }
        {
            int c = tid;
            float s2 = rdv(ps.bn2, c, isbf) * rsqrtf(rdv(ps.bn2, 768 + c, isbf) + EPSBN);
            ws[P_BP2 + c] = rdv(ps.c2b, c, isbf) * s2 + (rdv(ps.bn2, 256 + c, isbf) - rdv(ps.bn2, 512 + c, isbf) * s2);
            float s5 = rdv(ps.blk1bn, c, isbf) * rsqrtf(rdv(ps.blk1bn, 768 + c, isbf) + EPSBN);
            ws[P_BP4 + c] = rdv(ps.blk1b, c, isbf) * s5 + (rdv(ps.blk1bn, 256 + c, isbf) - rdv(ps.blk1bn, 512 + c, isbf) * s5);
        }
        if (tid < 128) {
            int c = tid;
            float s1 = rdv(ps.bn1, c, isbf) * rsqrtf(rdv(ps.bn1, 384 + c, isbf) + EPSBN);
            ws[P_BP1 + c] = rdv(ps.c1b, c, isbf) * s1 + (rdv(ps.bn1, 128 + c, isbf) - rdv(ps.bn1, 256 + c, isbf) * s1);
            float s6 = rdv(ps.blk2bn, c, isbf) * rsqrtf(rdv(ps.blk2bn, 384 + c, isbf) + EPSBN);
            ws[P_BP5 + c] = rdv(ps.blk2b, c, isbf) * s6 + (rdv(ps.blk2bn, 128 + c, isbf) - rdv(ps.blk2bn, 256 + c, isbf) * s6);
        }
    } else {
        u32* z = (u32*)(ws + S_MAXF);
        for (int i = tid; i < 12288; i += 256) z[i] = 0u;
        if (tid == 0) ((u32*)ws)[0] = (u32)isbf;
    }
}

// ================= K1: fused t-net + pct (one block per batch) =================
__global__ __launch_bounds__(256) void k_tnet(const float* __restrict__ inp,
                                              const float* __restrict__ w,
                                              const float* __restrict__ bias,
                                              const float* __restrict__ bn,
                                              const float* __restrict__ w1, const float* __restrict__ b1,
                                              const float* __restrict__ bn2p,
                                              const float* __restrict__ w2, const float* __restrict__ b2,
                                              float* __restrict__ pct) {
    __shared__ float pts[6144];     // 2048 x 3
    __shared__ float wred[4][64];
    __shared__ float x1v[64];
    __shared__ float x2v[64];
    __shared__ float tf[9];
    int b = blockIdx.x, tid = threadIdx.x;
    const float* ip = inp + (size_t)b * 2048 * 3;
#pragma unroll
    for (int i = 0; i < 24; i++) pts[tid + i * 256] = ip[tid + i * 256];

    int c = tid & 63, pg = tid >> 6;
    float w0 = w[c], w1c = w[64 + c], w2c = w[128 + c], bi = bias[c];
    float g = bn[c], be = bn[64 + c], m = bn[128 + c], v = bn[192 + c];
    float s = g * rsqrtf(v + EPSBN), t = be - m * s;
    __syncthreads();

    float vmax = 0.f;
    int pbase = pg * 512;
#pragma unroll 4
    for (int p = 0; p < 512; p++) {
        float x0 = pts[(pbase + p) * 3], x1 = pts[(pbase + p) * 3 + 1], x2 = pts[(pbase + p) * 3 + 2];
        float z = x0 * w0 + x1 * w1c + x2 * w2c + bi;
        vmax = fmaxf(vmax, z * s + t);
    }
    wred[pg][c] = vmax;
    __syncthreads();
    if (tid < 64) {
        float mm = fmaxf(fmaxf(wred[0][tid], wred[1][tid]), fmaxf(wred[2][tid], wred[3][tid]));
        x1v[tid] = relu(mm);
    }
    __syncthreads();
    if (tid < 64) {
        float acc = b1[tid];
        for (int j = 0; j < 64; j++) acc += x1v[j] * w1[j * 64 + tid];
        float g2 = bn2p[tid], be2 = bn2p[64 + tid], m2 = bn2p[128 + tid], v2 = bn2p[192 + tid];
        float s2 = g2 * rsqrtf(v2 + EPSBN);
        x2v[tid] = relu(acc * s2 + (be2 - m2 * s2));
    }
    __syncthreads();
    if (tid < 9) {
        float a = b2[tid];
        for (int j = 0; j < 64; j++) a += x2v[j] * w2[j * 9 + tid];
        tf[tid] = a;
    }
    __syncthreads();
    float t0 = tf[0], t1 = tf[1], t2 = tf[2], t3 = tf[3], t4 = tf[4];
    float t5 = tf[5], t6 = tf[6], t7 = tf[7], t8 = tf[8];
    float* op = pct + (size_t)b * 2048 * 3;
#pragma unroll
    for (int i = 0; i < 8; i++) {
        int p = tid + i * 256;
        float x0 = pts[p * 3], x1 = pts[p * 3 + 1], x2 = pts[p * 3 + 2];
        op[p * 3]     = x0 * t0 + x1 * t3 + x2 * t6;
        op[p * 3 + 1] = x0 * t1 + x1 * t4 + x2 * t7;
        op[p * 3 + 2] = x0 * t2 + x1 * t5 + x2 * t8;
    }
}

// ================= K2: fused feat (even blocks) + mlp-main (odd blocks), 35KB LDS =================
__global__ __launch_bounds__(256, 4) void k_featmlp(
    const float* __restrict__ pct, const int* __restrict__ indices,
    const u16* __restrict__ w1t, const float* __restrict__ bp1,
    const u16* __restrict__ w2t, const float* __restrict__ bp2,
    u32* __restrict__ maxfeats,
    const float* __restrict__ w3s, const float* __restrict__ b3s,
    const u16* __restrict__ w4t, const float* __restrict__ bp4,
    const u16* __restrict__ w5t, const float* __restrict__ bp5,
    u32* __restrict__ netmax) {
    __shared__ __align__(16) char SM[35328];
    int bx = blockIdx.x, tid = threadIdx.x;
    int part = bx & 1;
    int idx = bx >> 1;
    int b = idx >> 5, sub = idx & 31;
    int lane = tid & 63, wv = tid >> 6;
    int rw = lane & 15, kq = lane >> 4;
    int axor = (rw & 7) << 4;

    if (part == 0) {
        // ---------------- feat: gather -> 96->128 -> 128->256 -> channel max ----------------
        char* ftA = SM;                       // [64][128] u16 pitch 256B swizzled (96 used)
        char* h1B = SM + 16384;               // [64][128] u16 pitch 256B swizzled
        float* sp1 = (float*)(SM + 32768);    // 128
        float* sp2 = (float*)(SM + 33280);    // 256
        int n0p = sub * 64;
        sp2[tid] = bp2[tid];
        if (tid < 128) sp1[tid] = bp1[tid];
        {
            const float* pb = pct + (size_t)b * 2048 * 3;
            const int* ib = indices + ((size_t)b * 2048 + n0p) * 32;
#pragma unroll
            for (int r = 0; r < 8; r++) {
                int i = tid + 256 * r;
                int p = i >> 5, k = i & 31;
                int idxp = ib[p * 32 + k];
                const float* s = pb + (size_t)idxp * 3;
                int sw = (p & 7) << 4;
                int base = p * 256 + 6 * k;
                *(u16*)(ftA + ((base) ^ sw))     = f2bf(s[0]);
                *(u16*)(ftA + ((base + 2) ^ sw)) = f2bf(s[1]);
                *(u16*)(ftA + ((base + 4) ^ sw)) = f2bf(s[2]);
            }
        }
        __syncthreads();
        // GEMM A: [64][96] x W1T[128][96]
        {
            f32x4 acc[4][2];
#pragma unroll
            for (int m = 0; m < 4; m++)
#pragma unroll
                for (int n = 0; n < 2; n++) acc[m][n] = (f32x4){0.f, 0.f, 0.f, 0.f};
            const char* W = (const char*)w1t;
            int nb = wv * 32;
#pragma unroll
            for (int ks = 0; ks < 3; ks++) {
                int kb = ks * 64 + kq * 16;
                bf16x8 b0 = *(const bf16x8*)(W + (nb + rw) * 192 + kb);
                bf16x8 b1 = *(const bf16x8*)(W + (nb + 16 + rw) * 192 + kb);
                bf16x8 a0 = *(const bf16x8*)(ftA + (((rw) * 256 + kb) ^ axor));
                bf16x8 a1 = *(const bf16x8*)(ftA + (((rw + 16) * 256 + kb) ^ axor));
                bf16x8 a2 = *(const bf16x8*)(ftA + (((rw + 32) * 256 + kb) ^ axor));
                bf16x8 a3 = *(const bf16x8*)(ftA + (((rw + 48) * 256 + kb) ^ axor));
                acc[0][0] = MFMA16(a0, b0, acc[0][0]); acc[0][1] = MFMA16(a0, b1, acc[0][1]);
                acc[1][0] = MFMA16(a1, b0, acc[1][0]); acc[1][1] = MFMA16(a1, b1, acc[1][1]);
                acc[2][0] = MFMA16(a2, b0, acc[2][0]); acc[2][1] = MFMA16(a2, b1, acc[2][1]);
                acc[3][0] = MFMA16(a3, b0, acc[3][0]); acc[3][1] = MFMA16(a3, b1, acc[3][1]);
            }
#pragma unroll
            for (int nt = 0; nt < 2; nt++) {
                int c = nb + nt * 16 + rw;
                float bb = sp1[c];
#pragma unroll
                for (int m = 0; m < 4; m++)
#pragma unroll
                    for (int r = 0; r < 4; r++) {
                        int rr = m * 16 + kq * 4 + r;
                        float h = relu(acc[m][nt][r] + bb);
                        *(u16*)(h1B + ((rr * 256 + c * 2) ^ ((rr & 7) << 4))) = f2bf(h);
                    }
            }
        }
        __syncthreads();
        // GEMM B: [64][128] x W2T[256][128] -> channel max
        {
            f32x4 acc[4][4];
#pragma unroll
            for (int m = 0; m < 4; m++)
#pragma unroll
                for (int n = 0; n < 4; n++) acc[m][n] = (f32x4){0.f, 0.f, 0.f, 0.f};
            const char* W = (const char*)w2t;
            int nb = wv * 64;
#pragma unroll
            for (int ks = 0; ks < 4; ks++) {
                int kb = ks * 64 + kq * 16;
                bf16x8 a0 = *(const bf16x8*)(h1B + (((rw) * 256 + kb) ^ axor));
                bf16x8 a1 = *(const bf16x8*)(h1B + (((rw + 16) * 256 + kb) ^ axor));
                bf16x8 a2 = *(const bf16x8*)(h1B + (((rw + 32) * 256 + kb) ^ axor));
                bf16x8 a3 = *(const bf16x8*)(h1B + (((rw + 48) * 256 + kb) ^ axor));
#pragma unroll
                for (int nt = 0; nt < 4; nt++) {
                    bf16x8 bv = *(const bf16x8*)(W + (nb + nt * 16 + rw) * 256 + kb);
                    acc[0][nt] = MFMA16(a0, bv, acc[0][nt]);
                    acc[1][nt] = MFMA16(a1, bv, acc[1][nt]);
                    acc[2][nt] = MFMA16(a2, bv, acc[2][nt]);
                    acc[3][nt] = MFMA16(a3, bv, acc[3][nt]);
                }
            }
#pragma unroll
            for (int nt = 0; nt < 4; nt++) {
                int c = nb + nt * 16 + rw;
                float bb = sp2[c];
                float vm = 0.f;
#pragma unroll
                for (int m = 0; m < 4; m++)
#pragma unroll
                    for (int r = 0; r < 4; r++)
                        vm = fmaxf(vm, relu(acc[m][nt][r] + bb));
                vm = fmaxf(vm, __shfl_xor(vm, 16));
                vm = fmaxf(vm, __shfl_xor(vm, 32));
                if (kq == 0) atomicMax(&maxfeats[b * 256 + c], __float_as_uint(vm));
            }
        }
    } else {
        // ---------------- mlp-main: rows sub*64.., 3->512->256->128 + row max ----------------
        char* hA0 = SM;                       // [64][64] u16 pitch 128B swizzled
        char* hA1 = SM + 8192;
        char* HB  = SM + 16384;               // [32][256] u16 pitch 512B swizzled (half rows)
        float* rows4 = (float*)(SM + 32768);  // [64][4]
        float* sb4 = (float*)(SM + 33792);    // 256
        float* sb5 = (float*)(SM + 34816);    // 128
        int r0 = sub * 64;

        sb4[tid] = bp4[tid];
        if (tid < 128) sb5[tid] = bp5[tid];
        if (tid < 64) {
            const float* s = pct + ((size_t)b * 2048 + r0 + tid) * 3;
            rows4[tid * 4] = s[0]; rows4[tid * 4 + 1] = s[1]; rows4[tid * 4 + 2] = s[2];
        }
        __syncthreads();

        auto phase1 = [&](int c, char* dst) {
            int c2 = (tid & 31) * 2;
            int rg = tid >> 5;
            int ch = c * 64 + c2;
            float wa0 = w3s[ch], wa1 = w3s[512 + ch], wa2 = w3s[1024 + ch], ba = b3s[ch];
            float wb0 = w3s[ch + 1], wb1 = w3s[513 + ch], wb2 = w3s[1025 + ch], bb2 = b3s[ch + 1];
#pragma unroll
            for (int r = 0; r < 8; r++) {
                int row = rg * 8 + r;
                float x0 = rows4[row * 4], x1 = rows4[row * 4 + 1], x2 = rows4[row * 4 + 2];
                float ha = relu(x0 * wa0 + x1 * wa1 + x2 * wa2 + ba);
                float hb = relu(x0 * wb0 + x1 * wb1 + x2 * wb2 + bb2);
                u32 pk = (u32)f2bf(ha) | ((u32)f2bf(hb) << 16);
                *(u32*)(dst + ((row * 128 + c2 * 2) ^ ((row & 7) << 4))) = pk;
            }
        };

        phase1(0, hA0);
        __syncthreads();

        // phase 2: [64][512] x W4T[256][512] -> acc
        f32x4 acc[4][4];
#pragma unroll
        for (int m = 0; m < 4; m++)
#pragma unroll
            for (int n = 0; n < 4; n++) acc[m][n] = (f32x4){0.f, 0.f, 0.f, 0.f};
        {
            const char* W = (const char*)w4t;
            int nb = wv * 64;
            for (int c = 0; c < 8; c++) {
                bf16x8 bfr[2][4];
#pragma unroll
                for (int ksl = 0; ksl < 2; ksl++)
#pragma unroll
                    for (int nt = 0; nt < 4; nt++)
                        bfr[ksl][nt] = *(const bf16x8*)(W + (nb + nt * 16 + rw) * 1024 + c * 128 + ksl * 64 + kq * 16);
                if (c < 7) phase1(c + 1, (c & 1) ? hA0 : hA1);
                const char* A = (c & 1) ? hA1 : hA0;
#pragma unroll
                for (int ksl = 0; ksl < 2; ksl++) {
                    int kb = ksl * 64 + kq * 16;
                    bf16x8 a0 = *(const bf16x8*)(A + (((rw) * 128 + kb) ^ axor));
                    bf16x8 a1 = *(const bf16x8*)(A + (((rw + 16) * 128 + kb) ^ axor));
                    bf16x8 a2 = *(const bf16x8*)(A + (((rw + 32) * 128 + kb) ^ axor));
                    bf16x8 a3 = *(const bf16x8*)(A + (((rw + 48) * 128 + kb) ^ axor));
#pragma unroll
                    for (int nt = 0; nt < 4; nt++) {
                        acc[0][nt] = MFMA16(a0, bfr[ksl][nt], acc[0][nt]);
                        acc[1][nt] = MFMA16(a1, bfr[ksl][nt], acc[1][nt]);
                        acc[2][nt] = MFMA16(a2, bfr[ksl][nt], acc[2][nt]);
                        acc[3][nt] = MFMA16(a3, bfr[ksl][nt], acc[3][nt]);
                    }
                }
                __syncthreads();
            }
        }
        // epilogue + phase 3 in two 32-row halves
        float vm[2] = {0.f, 0.f};
        const char* W5 = (const char*)w5t;
        int nb2 = wv * 32;
#pragma unroll
        for (int h = 0; h < 2; h++) {
            // write rows h*32..h*32+31 of h256 into HB[32][256]
#pragma unroll
            for (int nt = 0; nt < 4; nt++) {
                int c = wv * 64 + nt * 16 + rw;
                float bb = sb4[c];
#pragma unroll
                for (int m = 0; m < 2; m++) {
                    int mm = h * 2 + m;
#pragma unroll
                    for (int r = 0; r < 4; r++) {
                        int rr = m * 16 + kq * 4 + r;   // local row 0..31
                        float hh = relu(acc[mm][nt][r] + bb);
                        *(u16*)(HB + ((rr * 512 + c * 2) ^ ((rr & 7) << 4))) = f2bf(hh);
                    }
                }
            }
            __syncthreads();
            // phase3 half: [32][256] x W5T[128][256]
            f32x4 acc3[2][2];
#pragma unroll
            for (int m = 0; m < 2; m++)
#pragma unroll
                for (int n = 0; n < 2; n++) acc3[m][n] = (f32x4){0.f, 0.f, 0.f, 0.f};
#pragma unroll
            for (int ks = 0; ks < 8; ks++) {
                int kb = ks * 64 + kq * 16;
                bf16x8 b0 = *(const bf16x8*)(W5 + (nb2 + rw) * 512 + kb);
                bf16x8 b1 = *(const bf16x8*)(W5 + (nb2 + 16 + rw) * 512 + kb);
                bf16x8 a0 = *(const bf16x8*)(HB + (((rw) * 512 + kb) ^ axor));
                bf16x8 a1 = *(const bf16x8*)(HB + (((rw + 16) * 512 + kb) ^ axor));
                acc3[0][0] = MFMA16(a0, b0, acc3[0][0]); acc3[0][1] = MFMA16(a0, b1, acc3[0][1]);
                acc3[1][0] = MFMA16(a1, b0, acc3[1][0]); acc3[1][1] = MFMA16(a1, b1, acc3[1][1]);
            }
#pragma unroll
            for (int nt = 0; nt < 2; nt++) {
                int c = nb2 + nt * 16 + rw;
                float bb = sb5[c];
#pragma unroll
                for (int m = 0; m < 2; m++)
#pragma unroll
                    for (int r = 0; r < 4; r++)
                        vm[nt] = fmaxf(vm[nt], relu(acc3[m][nt][r] + bb));
            }
            __syncthreads();
        }
#pragma unroll
        for (int nt = 0; nt < 2; nt++) {
            int c = nb2 + nt * 16 + rw;
            float v = vm[nt];
            v = fmaxf(v, __shfl_xor(v, 16));
            v = fmaxf(v, __shfl_xor(v, 32));
            if (kq == 0) atomicMax(&netmax[b * 128 + c], __float_as_uint(v));
        }
    }
}

// ================= K3: g-row tail + final bn/out =================
__global__ __launch_bounds__(256) void k_gtail(const u32* __restrict__ maxfeats,
                                               const float* __restrict__ bn3p,
                                               const float* __restrict__ dw, const float* __restrict__ db,
                                               const float* __restrict__ w3s, const float* __restrict__ b3s,
                                               const u16* __restrict__ w4t, const float* __restrict__ bp4,
                                               const u16* __restrict__ w5t, const float* __restrict__ bp5,
                                               u32* __restrict__ netmax,
                                               const float* __restrict__ bng,
                                               const u32* __restrict__ flag,
                                               void* __restrict__ out) {
    __shared__ float red[3][256];
    __shared__ float h512[512];
    __shared__ float h256[256];
    __shared__ float gv[4];
    int b = blockIdx.x, c = threadIdx.x;
    float mf = __uint_as_float(maxfeats[b * 256 + c]);
    float g = bn3p[c], be = bn3p[256 + c], m = bn3p[512 + c], v = bn3p[768 + c];
    float s = g * rsqrtf(v + EPSBN);
    float y = mf * s + (be - m * s);  // no relu on bn3
    red[0][c] = y * dw[c * 3 + 0];
    red[1][c] = y * dw[c * 3 + 1];
    red[2][c] = y * dw[c * 3 + 2];
    __syncthreads();
    for (int st = 128; st > 0; st >>= 1) {
        if (c < st) {
            red[0][c] += red[0][c + st];
            red[1][c] += red[1][c + st];
            red[2][c] += red[2][c + st];
        }
        __syncthreads();
    }
    if (c < 3) gv[c] = red[c][0] + db[c];
    __syncthreads();
    float g0 = gv[0], g1 = gv[1], g2 = gv[2];
    for (int h = c; h < 512; h += 256)
        h512[h] = relu(g0 * w3s[h] + g1 * w3s[512 + h] + g2 * w3s[1024 + h] + b3s[h]);
    __syncthreads();
    {
        float acc = 0.f;
        const bf16x8* wr = (const bf16x8*)(w4t + (size_t)c * 512);
        for (int i = 0; i < 64; i++) {
            bf16x8 vv = wr[i];
#pragma unroll
            for (int j = 0; j < 8; j++) acc += h512[i * 8 + j] * bf2f((u16)vv[j]);
        }
        h256[c] = relu(acc + bp4[c]);
    }
    __syncthreads();
    if (c < 128) {
        float acc = 0.f;
        const bf16x8* wr = (const bf16x8*)(w5t + (size_t)c * 256);
        for (int i = 0; i < 32; i++) {
            bf16x8 vv = wr[i];
#pragma unroll
            for (int j = 0; j < 8; j++) acc += h256[i * 8 + j] * bf2f((u16)vv[j]);
        }
        u32 mybits = __float_as_uint(relu(acc + bp5[c]));
        u32 old = atomicMax(&netmax[b * 128 + c], mybits);
        u32 fin = old > mybits ? old : mybits;
        // final bn_globf + store
        float vv = __uint_as_float(fin);
        float gg = bng[c], bee = bng[128 + c], mm = bng[256 + c], va = bng[384 + c];
        float ss = gg * rsqrtf(va + EPSBN);
        float val = vv * ss + (bee - mm * ss);
        int oi = b * 128 + c;
        if (flag[0]) ((u16*)out)[oi] = f2bf(val);
        else ((float*)out)[oi] = val;
    }
}

extern "C" void kernel_launch(void* const* d_in, const int* in_sizes, int n_in,
                              void* d_out, int out_size, void* d_ws, size_t ws_size,
                              hipStream_t stream) {
    float* ws = (float*)d_ws;
    const int* indices = (const int*)d_in[1];

    SmallCv sc;
    {
        static const int srcix[12] = {2, 3, 4, 5, 6, 7, 8, 9, 16, 17, 18, 28};
        static const int nels[12] = {192, 64, 256, 4096, 64, 256, 576, 9, 1024, 768, 3, 512};
        static const int offs[12] = {A_TC1W, A_TC1B, A_TBN1, A_TD1W, A_TD1B, A_TBN2, A_TD2W, A_TD2B,
                                     A_BN3, A_D1W, A_D1B, A_BNGF};
        for (int i = 0; i < 12; i++) { sc.src[i] = d_in[srcix[i]]; sc.n[i] = nels[i]; sc.off[i] = offs[i]; }
    }
    PrepWA pw;
    pw.src[0] = d_in[10]; pw.bn[0] = d_in[12]; pw.K[0] = 96;  pw.logN[0] = 7; pw.base[0] = 0;  pw.dstoff[0] = T_C1WT;
    pw.src[1] = d_in[13]; pw.bn[1] = d_in[15]; pw.K[1] = 128; pw.logN[1] = 8; pw.base[1] = 6;  pw.dstoff[1] = T_C2WT;
    pw.src[2] = d_in[22]; pw.bn[2] = d_in[24]; pw.K[2] = 512; pw.logN[2] = 8; pw.base[2] = 22; pw.dstoff[2] = T_W4T;
    pw.src[3] = d_in[25]; pw.bn[3] = d_in[27]; pw.K[3] = 256; pw.logN[3] = 7; pw.base[3] = 86; pw.dstoff[3] = T_W5T;
    PrepSm ps;
    ps.bn4 = d_in[21]; ps.c3w = d_in[19]; ps.c3b = d_in[20];
    ps.bn2 = d_in[15]; ps.c2b = d_in[14];
    ps.blk1bn = d_in[24]; ps.blk1b = d_in[23];
    ps.bn1 = d_in[12]; ps.c1b = d_in[11];
    ps.blk2bn = d_in[27]; ps.blk2b = d_in[26];

    k_prep<<<140, 256, 0, stream>>>(sc, pw, ps, d_in[0], (const u16*)d_in[4], ws);

    k_tnet<<<32, 256, 0, stream>>>(ws + A_INPUTS, ws + A_TC1W, ws + A_TC1B, ws + A_TBN1,
                                   ws + A_TD1W, ws + A_TD1B, ws + A_TBN2,
                                   ws + A_TD2W, ws + A_TD2B, ws + S_PCT);

    k_featmlp<<<2048, 256, 0, stream>>>(ws + S_PCT, indices,
                                        (const u16*)(ws + T_C1WT), ws + P_BP1,
                                        (const u16*)(ws + T_C2WT), ws + P_BP2,
                                        (u32*)(ws + S_MAXF),
                                        ws + P_W3S, ws + P_B3S,
                                        (const u16*)(ws + T_W4T), ws + P_BP4,
                                        (const u16*)(ws + T_W5T), ws + P_BP5,
                                        (u32*)(ws + S_NETMAX));

    k_gtail<<<32, 256, 0, stream>>>((u32*)(ws + S_MAXF), ws + A_BN3, ws + A_D1W, ws + A_D1B,
                                    ws + P_W3S, ws + P_B3S,
                                    (const u16*)(ws + T_W4T), ws + P_BP4,
                                    (const u16*)(ws + T_W5T), ws + P_BP5,
                                    (u32*)(ws + S_NETMAX),
                                    ws + A_BNGF, (u32*)ws, d_out);
}

// Round 11
// 268.042 us; speedup vs baseline: 1.1844x; 1.1844x over previous
//
#include <hip/hip_runtime.h>

typedef unsigned short u16;
typedef unsigned int u32;
typedef __attribute__((ext_vector_type(8))) short bf16x8;
typedef __attribute__((ext_vector_type(4))) float f32x4;

#define EPSBN 0.001f
#define MFMA16(a, b, c) __builtin_amdgcn_mfma_f32_16x16x32_bf16(a, b, c, 0, 0, 0)

__device__ __forceinline__ float bf2f(u16 u) {
    return __uint_as_float(((u32)u) << 16);
}
__device__ __forceinline__ u16 f2bf(float f) {
    u32 u = __float_as_uint(f);
    u32 r = u + 0x7FFFu + ((u >> 16) & 1u);
    return (u16)(r >> 16);
}
__device__ __forceinline__ float relu(float x) { return x > 0.f ? x : 0.f; }
__device__ __forceinline__ float rdv(const void* p, int i, int isbf) {
    return isbf ? bf2f(((const u16*)p)[i]) : ((const float*)p)[i];
}

// ---------------- ws layout (float offsets) ----------------
// [0]: flag u32
#define A_INPUTS 64       // 196608
#define A_TC1W  196672
#define A_TC1B  196864
#define A_TBN1  196928
#define A_TD1W  197184
#define A_TD1B  201280
#define A_TBN2  201344
#define A_TD2W  201600
#define A_TD2B  202176
#define A_BN3   249216
#define A_D1W   250240
#define A_D1B   251008
#define A_BNGF  420928
#define S_PCT   423808    // 196608 (32*2048*3 f32)
// zeroed region: [S_MAXF, S_MAXF+12288)
#define S_MAXF  620544    // 8192 u32 (maxfeats)
#define S_NETMAX 628736   // 4096 u32
// bf16 transposed+scaled weight arenas
#define T_C1WT  634880    // 128x96  u16
#define T_C2WT  641024    // 256x128 u16
#define T_W4T   657408    // 256x512 u16
#define T_W5T   722944    // 128x256 u16
// folded small params (f32)
#define P_W3S   739328    // 1536
#define P_B3S   740864    // 512
#define P_BP1   741376    // 128
#define P_BP2   741504    // 256
#define P_BP4   741760    // 256
#define P_BP5   742016    // 128
// end 742144 floats = 2.97 MB

struct SmallCv { const void* src[12]; int n[12]; int off[12]; };
struct PrepWA { const void* src[4]; const void* bn[4]; int K[4]; int logN[4]; int base[4]; int dstoff[4]; };
struct PrepSm { const void *bn4, *c3w, *c3b, *bn2, *c2b, *blk1bn, *blk1b, *bn1, *c1b, *blk2bn, *blk2b; };

// ================= K0: prep everything (140 blocks) =================
__global__ __launch_bounds__(256) void k_prep(SmallCv sc, PrepWA pw, PrepSm ps,
                                              const void* __restrict__ inputs_raw,
                                              const u16* __restrict__ tbn1_raw,
                                              float* __restrict__ ws) {
    __shared__ float tile[32][65];
    __shared__ float scol[64];
    int isbf = 1;
    for (int i = 0; i < 16; i += 2) {
        u16 v = tbn1_raw[i];
        if (v < 0x3E00u || v > 0x4080u) isbf = 0;
    }
    int bx = blockIdx.x, tid = threadIdx.x;
    if (bx < 32) {
        float* dst = ws + A_INPUTS;
        for (int i = bx * 256 + tid; i < 196608; i += 8192) dst[i] = rdv(inputs_raw, i, isbf);
    } else if (bx < 36) {
        int t0 = (bx - 32) * 3;
        for (int t = t0; t < t0 + 3; t++) {
            int n = sc.n[t];
            float* dst = ws + sc.off[t];
            for (int i = tid; i < n; i += 256) dst[i] = rdv(sc.src[t], i, isbf);
        }
    } else if (bx < 138) {
        int blk = bx - 36;
        int t = (blk < 6) ? 0 : (blk < 22) ? 1 : (blk < 86) ? 2 : 3;
        int tt = blk - pw.base[t];
        int N = 1 << pw.logN[t];
        int K = pw.K[t];
        int ct = N >> 6;
        int k0 = (tt / ct) * 32, c0 = (tt % ct) * 64;
        if (tid < 64) {
            int c = c0 + tid;
            scol[tid] = rdv(pw.bn[t], c, isbf) * rsqrtf(rdv(pw.bn[t], 3 * N + c, isbf) + EPSBN);
        }
        __syncthreads();
#pragma unroll
        for (int pr = 0; pr < 8; pr++) {
            int kr = pr * 4 + (tid >> 6), cc = tid & 63;
            tile[kr][cc] = rdv(pw.src[t], (k0 + kr) * N + c0 + cc, isbf) * scol[cc];
        }
        __syncthreads();
        u32* d32 = (u32*)((u16*)(ws + pw.dstoff[t]));
#pragma unroll
        for (int pw2 = 0; pw2 < 4; pw2++) {
            int cr = pw2 * 16 + (tid >> 4);
            int kp = tid & 15;
            u32 pk = (u32)f2bf(tile[kp * 2][cr]) | ((u32)f2bf(tile[kp * 2 + 1][cr]) << 16);
            d32[(((c0 + cr) * K + k0) >> 1) + kp] = pk;
        }
    } else if (bx == 138) {
        for (int c = tid; c < 512; c += 256) {
            float s = rdv(ps.bn4, c, isbf) * rsqrtf(rdv(ps.bn4, 1536 + c, isbf) + EPSBN);
            float t = rdv(ps.bn4, 512 + c, isbf) - rdv(ps.bn4, 1024 + c, isbf) * s;
            ws[P_W3S + c]        = rdv(ps.c3w, c, isbf) * s;
            ws[P_W3S + 512 + c]  = rdv(ps.c3w, 512 + c, isbf) * s;
            ws[P_W3S + 1024 + c] = rdv(ps.c3w, 1024 + c, isbf) * s;
            ws[P_B3S + c] = rdv(ps.c3b, c, isbf) * s + t;
        }
        {
            int c = tid;
            float s2 = rdv(ps.bn2, c, isbf) * rsqrtf(rdv(ps.bn2, 768 + c, isbf) + EPSBN);
            ws[P_BP2 + c] = rdv(ps.c2b, c, isbf) * s2 + (rdv(ps.bn2, 256 + c, isbf) - rdv(ps.bn2, 512 + c, isbf) * s2);
            float s5 = rdv(ps.blk1bn, c, isbf) * rsqrtf(rdv(ps.blk1bn, 768 + c, isbf) + EPSBN);
            ws[P_BP4 + c] = rdv(ps.blk1b, c, isbf) * s5 + (rdv(ps.blk1bn, 256 + c, isbf) - rdv(ps.blk1bn, 512 + c, isbf) * s5);
        }
        if (tid < 128) {
            int c = tid;
            float s1 = rdv(ps.bn1, c, isbf) * rsqrtf(rdv(ps.bn1, 384 + c, isbf) + EPSBN);
            ws[P_BP1 + c] = rdv(ps.c1b, c, isbf) * s1 + (rdv(ps.bn1, 128 + c, isbf) - rdv(ps.bn1, 256 + c, isbf) * s1);
            float s6 = rdv(ps.blk2bn, c, isbf) * rsqrtf(rdv(ps.blk2bn, 384 + c, isbf) + EPSBN);
            ws[P_BP5 + c] = rdv(ps.blk2b, c, isbf) * s6 + (rdv(ps.blk2bn, 128 + c, isbf) - rdv(ps.blk2bn, 256 + c, isbf) * s6);
        }
    } else {
        u32* z = (u32*)(ws + S_MAXF);
        for (int i = tid; i < 12288; i += 256) z[i] = 0u;
        if (tid == 0) ((u32*)ws)[0] = (u32)isbf;
    }
}

// ================= K1: fused t-net + pct (one block per batch) =================
__global__ __launch_bounds__(256) void k_tnet(const float* __restrict__ inp,
                                              const float* __restrict__ w,
                                              const float* __restrict__ bias,
                                              const float* __restrict__ bn,
                                              const float* __restrict__ w1, const float* __restrict__ b1,
                                              const float* __restrict__ bn2p,
                                              const float* __restrict__ w2, const float* __restrict__ b2,
                                              float* __restrict__ pct) {
    __shared__ float pts[6144];     // 2048 x 3
    __shared__ float wred[4][64];
    __shared__ float x1v[64];
    __shared__ float x2v[64];
    __shared__ float tf[9];
    int b = blockIdx.x, tid = threadIdx.x;
    const float* ip = inp + (size_t)b * 2048 * 3;
#pragma unroll
    for (int i = 0; i < 24; i++) pts[tid + i * 256] = ip[tid + i * 256];

    int c = tid & 63, pg = tid >> 6;
    float w0 = w[c], w1c = w[64 + c], w2c = w[128 + c], bi = bias[c];
    float g = bn[c], be = bn[64 + c], m = bn[128 + c], v = bn[192 + c];
    float s = g * rsqrtf(v + EPSBN), t = be - m * s;
    __syncthreads();

    float vmax = 0.f;
    int pbase = pg * 512;
#pragma unroll 4
    for (int p = 0; p < 512; p++) {
        float x0 = pts[(pbase + p) * 3], x1 = pts[(pbase + p) * 3 + 1], x2 = pts[(pbase + p) * 3 + 2];
        float z = x0 * w0 + x1 * w1c + x2 * w2c + bi;
        vmax = fmaxf(vmax, z * s + t);
    }
    wred[pg][c] = vmax;
    __syncthreads();
    if (tid < 64) {
        float mm = fmaxf(fmaxf(wred[0][tid], wred[1][tid]), fmaxf(wred[2][tid], wred[3][tid]));
        x1v[tid] = relu(mm);
    }
    __syncthreads();
    if (tid < 64) {
        float acc = b1[tid];
        for (int j = 0; j < 64; j++) acc += x1v[j] * w1[j * 64 + tid];
        float g2 = bn2p[tid], be2 = bn2p[64 + tid], m2 = bn2p[128 + tid], v2 = bn2p[192 + tid];
        float s2 = g2 * rsqrtf(v2 + EPSBN);
        x2v[tid] = relu(acc * s2 + (be2 - m2 * s2));
    }
    __syncthreads();
    if (tid < 9) {
        float a = b2[tid];
        for (int j = 0; j < 64; j++) a += x2v[j] * w2[j * 9 + tid];
        tf[tid] = a;
    }
    __syncthreads();
    float t0 = tf[0], t1 = tf[1], t2 = tf[2], t3 = tf[3], t4 = tf[4];
    float t5 = tf[5], t6 = tf[6], t7 = tf[7], t8 = tf[8];
    float* op = pct + (size_t)b * 2048 * 3;
#pragma unroll
    for (int i = 0; i < 8; i++) {
        int p = tid + i * 256;
        float x0 = pts[p * 3], x1 = pts[p * 3 + 1], x2 = pts[p * 3 + 2];
        op[p * 3]     = x0 * t0 + x1 * t3 + x2 * t6;
        op[p * 3 + 1] = x0 * t1 + x1 * t4 + x2 * t7;
        op[p * 3 + 2] = x0 * t2 + x1 * t5 + x2 * t8;
    }
}

// ================= K2: fused feat/mlp, 35KB LDS, XCD-chunked swizzle =================
__global__ __launch_bounds__(256, 3) void k_featmlp(
    const float* __restrict__ pct, const int* __restrict__ indices,
    const u16* __restrict__ w1t, const float* __restrict__ bp1,
    const u16* __restrict__ w2t, const float* __restrict__ bp2,
    u32* __restrict__ maxfeats,
    const float* __restrict__ w3s, const float* __restrict__ b3s,
    const u16* __restrict__ w4t, const float* __restrict__ bp4,
    const u16* __restrict__ w5t, const float* __restrict__ bp5,
    u32* __restrict__ netmax) {
    __shared__ __align__(16) char SM[35328];
    int bx0 = blockIdx.x, tid = threadIdx.x;
    // XCD-chunked swizzle: 2048 blocks, 8 XCDs (XCD = bx0 % 8 assumed round-robin).
    // Each XCD gets a contiguous 256-block chunk = 4 batches -> pct working set 3MB <= 4MB L2.
    int bx = ((bx0 & 7) << 8) + (bx0 >> 3);
    int part = bx & 1;
    int idx = bx >> 1;
    int b = idx >> 5, sub = idx & 31;
    int lane = tid & 63, wv = tid >> 6;
    int rw = lane & 15, kq = lane >> 4;
    int axor = (rw & 7) << 4;

    if (part == 0) {
        // ---------------- feat: gather -> 96->128 -> 128->256 -> channel max ----------------
        char* ftA = SM;                       // [64][128] u16 pitch 256B swizzled (96 used)
        char* h1B = SM + 16384;               // [64][128] u16 pitch 256B swizzled
        float* sp1 = (float*)(SM + 32768);    // 128
        float* sp2 = (float*)(SM + 33280);    // 256
        int n0p = sub * 64;
        sp2[tid] = bp2[tid];
        if (tid < 128) sp1[tid] = bp1[tid];
        {
            const float* pb = pct + (size_t)b * 2048 * 3;
            const int* ib = indices + ((size_t)b * 2048 + n0p) * 32;
#pragma unroll
            for (int r = 0; r < 8; r++) {
                int i = tid + 256 * r;
                int p = i >> 5, k = i & 31;
                int idxp = ib[p * 32 + k];
                const float* s = pb + (size_t)idxp * 3;
                int sw = (p & 7) << 4;
                int base = p * 256 + 6 * k;
                *(u16*)(ftA + ((base) ^ sw))     = f2bf(s[0]);
                *(u16*)(ftA + ((base + 2) ^ sw)) = f2bf(s[1]);
                *(u16*)(ftA + ((base + 4) ^ sw)) = f2bf(s[2]);
            }
        }
        __syncthreads();
        // GEMM A: [64][96] x W1T[128][96]
        {
            f32x4 acc[4][2];
#pragma unroll
            for (int m = 0; m < 4; m++)
#pragma unroll
                for (int n = 0; n < 2; n++) acc[m][n] = (f32x4){0.f, 0.f, 0.f, 0.f};
            const char* W = (const char*)w1t;
            int nb = wv * 32;
#pragma unroll
            for (int ks = 0; ks < 3; ks++) {
                int kb = ks * 64 + kq * 16;
                bf16x8 b0 = *(const bf16x8*)(W + (nb + rw) * 192 + kb);
                bf16x8 b1 = *(const bf16x8*)(W + (nb + 16 + rw) * 192 + kb);
                bf16x8 a0 = *(const bf16x8*)(ftA + (((rw) * 256 + kb) ^ axor));
                bf16x8 a1 = *(const bf16x8*)(ftA + (((rw + 16) * 256 + kb) ^ axor));
                bf16x8 a2 = *(const bf16x8*)(ftA + (((rw + 32) * 256 + kb) ^ axor));
                bf16x8 a3 = *(const bf16x8*)(ftA + (((rw + 48) * 256 + kb) ^ axor));
                acc[0][0] = MFMA16(a0, b0, acc[0][0]); acc[0][1] = MFMA16(a0, b1, acc[0][1]);
                acc[1][0] = MFMA16(a1, b0, acc[1][0]); acc[1][1] = MFMA16(a1, b1, acc[1][1]);
                acc[2][0] = MFMA16(a2, b0, acc[2][0]); acc[2][1] = MFMA16(a2, b1, acc[2][1]);
                acc[3][0] = MFMA16(a3, b0, acc[3][0]); acc[3][1] = MFMA16(a3, b1, acc[3][1]);
            }
#pragma unroll
            for (int nt = 0; nt < 2; nt++) {
                int c = nb + nt * 16 + rw;
                float bb = sp1[c];
#pragma unroll
                for (int m = 0; m < 4; m++)
#pragma unroll
                    for (int r = 0; r < 4; r++) {
                        int rr = m * 16 + kq * 4 + r;
                        float h = relu(acc[m][nt][r] + bb);
                        *(u16*)(h1B + ((rr * 256 + c * 2) ^ ((rr & 7) << 4))) = f2bf(h);
                    }
            }
        }
        __syncthreads();
        // GEMM B: [64][128] x W2T[256][128] -> channel max
        {
            f32x4 acc[4][4];
#pragma unroll
            for (int m = 0; m < 4; m++)
#pragma unroll
                for (int n = 0; n < 4; n++) acc[m][n] = (f32x4){0.f, 0.f, 0.f, 0.f};
            const char* W = (const char*)w2t;
            int nb = wv * 64;
#pragma unroll
            for (int ks = 0; ks < 4; ks++) {
                int kb = ks * 64 + kq * 16;
                bf16x8 a0 = *(const bf16x8*)(h1B + (((rw) * 256 + kb) ^ axor));
                bf16x8 a1 = *(const bf16x8*)(h1B + (((rw + 16) * 256 + kb) ^ axor));
                bf16x8 a2 = *(const bf16x8*)(h1B + (((rw + 32) * 256 + kb) ^ axor));
                bf16x8 a3 = *(const bf16x8*)(h1B + (((rw + 48) * 256 + kb) ^ axor));
#pragma unroll
                for (int nt = 0; nt < 4; nt++) {
                    bf16x8 bv = *(const bf16x8*)(W + (nb + nt * 16 + rw) * 256 + kb);
                    acc[0][nt] = MFMA16(a0, bv, acc[0][nt]);
                    acc[1][nt] = MFMA16(a1, bv, acc[1][nt]);
                    acc[2][nt] = MFMA16(a2, bv, acc[2][nt]);
                    acc[3][nt] = MFMA16(a3, bv, acc[3][nt]);
                }
            }
#pragma unroll
            for (int nt = 0; nt < 4; nt++) {
                int c = nb + nt * 16 + rw;
                float bb = sp2[c];
                float vm = 0.f;
#pragma unroll
                for (int m = 0; m < 4; m++)
#pragma unroll
                    for (int r = 0; r < 4; r++)
                        vm = fmaxf(vm, relu(acc[m][nt][r] + bb));
                vm = fmaxf(vm, __shfl_xor(vm, 16));
                vm = fmaxf(vm, __shfl_xor(vm, 32));
                if (kq == 0) atomicMax(&maxfeats[b * 256 + c], __float_as_uint(vm));
            }
        }
    } else {
        // ---------------- mlp-main: rows sub*64.., 3->512->256->128 + row max ----------------
        char* hA0 = SM;                       // [64][64] u16 pitch 128B swizzled
        char* hA1 = SM + 8192;
        char* HB  = SM + 16384;               // [32][256] u16 pitch 512B swizzled (half rows)
        float* rows4 = (float*)(SM + 32768);  // [64][4]
        float* sb4 = (float*)(SM + 33792);    // 256
        float* sb5 = (float*)(SM + 34816);    // 128
        int r0 = sub * 64;

        sb4[tid] = bp4[tid];
        if (tid < 128) sb5[tid] = bp5[tid];
        if (tid < 64) {
            const float* s = pct + ((size_t)b * 2048 + r0 + tid) * 3;
            rows4[tid * 4] = s[0]; rows4[tid * 4 + 1] = s[1]; rows4[tid * 4 + 2] = s[2];
        }
        __syncthreads();

        auto phase1 = [&](int c, char* dst) {
            int c2 = (tid & 31) * 2;
            int rg = tid >> 5;
            int ch = c * 64 + c2;
            float wa0 = w3s[ch], wa1 = w3s[512 + ch], wa2 = w3s[1024 + ch], ba = b3s[ch];
            float wb0 = w3s[ch + 1], wb1 = w3s[513 + ch], wb2 = w3s[1025 + ch], bb2 = b3s[ch + 1];
#pragma unroll
            for (int r = 0; r < 8; r++) {
                int row = rg * 8 + r;
                float x0 = rows4[row * 4], x1 = rows4[row * 4 + 1], x2 = rows4[row * 4 + 2];
                float ha = relu(x0 * wa0 + x1 * wa1 + x2 * wa2 + ba);
                float hb = relu(x0 * wb0 + x1 * wb1 + x2 * wb2 + bb2);
                u32 pk = (u32)f2bf(ha) | ((u32)f2bf(hb) << 16);
                *(u32*)(dst + ((row * 128 + c2 * 2) ^ ((row & 7) << 4))) = pk;
            }
        };

        phase1(0, hA0);
        __syncthreads();

        // phase 2: [64][512] x W4T[256][512] -> acc
        f32x4 acc[4][4];
#pragma unroll
        for (int m = 0; m < 4; m++)
#pragma unroll
            for (int n = 0; n < 4; n++) acc[m][n] = (f32x4){0.f, 0.f, 0.f, 0.f};
        {
            const char* W = (const char*)w4t;
            int nb = wv * 64;
            for (int c = 0; c < 8; c++) {
                bf16x8 bfr[2][4];
#pragma unroll
                for (int ksl = 0; ksl < 2; ksl++)
#pragma unroll
                    for (int nt = 0; nt < 4; nt++)
                        bfr[ksl][nt] = *(const bf16x8*)(W + (nb + nt * 16 + rw) * 1024 + c * 128 + ksl * 64 + kq * 16);
                if (c < 7) phase1(c + 1, (c & 1) ? hA0 : hA1);
                const char* A = (c & 1) ? hA1 : hA0;
#pragma unroll
                for (int ksl = 0; ksl < 2; ksl++) {
                    int kb = ksl * 64 + kq * 16;
                    bf16x8 a0 = *(const bf16x8*)(A + (((rw) * 128 + kb) ^ axor));
                    bf16x8 a1 = *(const bf16x8*)(A + (((rw + 16) * 128 + kb) ^ axor));
                    bf16x8 a2 = *(const bf16x8*)(A + (((rw + 32) * 128 + kb) ^ axor));
                    bf16x8 a3 = *(const bf16x8*)(A + (((rw + 48) * 128 + kb) ^ axor));
#pragma unroll
                    for (int nt = 0; nt < 4; nt++) {
                        acc[0][nt] = MFMA16(a0, bfr[ksl][nt], acc[0][nt]);
                        acc[1][nt] = MFMA16(a1, bfr[ksl][nt], acc[1][nt]);
                        acc[2][nt] = MFMA16(a2, bfr[ksl][nt], acc[2][nt]);
                        acc[3][nt] = MFMA16(a3, bfr[ksl][nt], acc[3][nt]);
                    }
                }
                __syncthreads();
            }
        }
        // epilogue + phase 3 in two 32-row halves
        float vm[2] = {0.f, 0.f};
        const char* W5 = (const char*)w5t;
        int nb2 = wv * 32;
#pragma unroll
        for (int h = 0; h < 2; h++) {
#pragma unroll
            for (int nt = 0; nt < 4; nt++) {
                int c = wv * 64 + nt * 16 + rw;
                float bb = sb4[c];
#pragma unroll
                for (int m = 0; m < 2; m++) {
                    int mm = h * 2 + m;
#pragma unroll
                    for (int r = 0; r < 4; r++) {
                        int rr = m * 16 + kq * 4 + r;   // local row 0..31
                        float hh = relu(acc[mm][nt][r] + bb);
                        *(u16*)(HB + ((rr * 512 + c * 2) ^ ((rr & 7) << 4))) = f2bf(hh);
                    }
                }
            }
            __syncthreads();
            // phase3 half: [32][256] x W5T[128][256]
            f32x4 acc3[2][2];
#pragma unroll
            for (int m = 0; m < 2; m++)
#pragma unroll
                for (int n = 0; n < 2; n++) acc3[m][n] = (f32x4){0.f, 0.f, 0.f, 0.f};
#pragma unroll
            for (int ks = 0; ks < 8; ks++) {
                int kb = ks * 64 + kq * 16;
                bf16x8 b0 = *(const bf16x8*)(W5 + (nb2 + rw) * 512 + kb);
                bf16x8 b1 = *(const bf16x8*)(W5 + (nb2 + 16 + rw) * 512 + kb);
                bf16x8 a0 = *(const bf16x8*)(HB + (((rw) * 512 + kb) ^ axor));
                bf16x8 a1 = *(const bf16x8*)(HB + (((rw + 16) * 512 + kb) ^ axor));
                acc3[0][0] = MFMA16(a0, b0, acc3[0][0]); acc3[0][1] = MFMA16(a0, b1, acc3[0][1]);
                acc3[1][0] = MFMA16(a1, b0, acc3[1][0]); acc3[1][1] = MFMA16(a1, b1, acc3[1][1]);
            }
#pragma unroll
            for (int nt = 0; nt < 2; nt++) {
                int c = nb2 + nt * 16 + rw;
                float bb = sb5[c];
#pragma unroll
                for (int m = 0; m < 2; m++)
#pragma unroll
                    for (int r = 0; r < 4; r++)
                        vm[nt] = fmaxf(vm[nt], relu(acc3[m][nt][r] + bb));
            }
            __syncthreads();
        }
#pragma unroll
        for (int nt = 0; nt < 2; nt++) {
            int c = nb2 + nt * 16 + rw;
            float v = vm[nt];
            v = fmaxf(v, __shfl_xor(v, 16));
            v = fmaxf(v, __shfl_xor(v, 32));
            if (kq == 0) atomicMax(&netmax[b * 128 + c], __float_as_uint(v));
        }
    }
}

// ================= K3: g-row tail + final bn/out =================
__global__ __launch_bounds__(256) void k_gtail(const u32* __restrict__ maxfeats,
                                               const float* __restrict__ bn3p,
                                               const float* __restrict__ dw, const float* __restrict__ db,
                                               const float* __restrict__ w3s, const float* __restrict__ b3s,
                                               const u16* __restrict__ w4t, const float* __restrict__ bp4,
                                               const u16* __restrict__ w5t, const float* __restrict__ bp5,
                                               u32* __restrict__ netmax,
                                               const float* __restrict__ bng,
                                               const u32* __restrict__ flag,
                                               void* __restrict__ out) {
    __shared__ float red[3][256];
    __shared__ float h512[512];
    __shared__ float h256[256];
    __shared__ float gv[4];
    int b = blockIdx.x, c = threadIdx.x;
    float mf = __uint_as_float(maxfeats[b * 256 + c]);
    float g = bn3p[c], be = bn3p[256 + c], m = bn3p[512 + c], v = bn3p[768 + c];
    float s = g * rsqrtf(v + EPSBN);
    float y = mf * s + (be - m * s);  // no relu on bn3
    red[0][c] = y * dw[c * 3 + 0];
    red[1][c] = y * dw[c * 3 + 1];
    red[2][c] = y * dw[c * 3 + 2];
    __syncthreads();
    for (int st = 128; st > 0; st >>= 1) {
        if (c < st) {
            red[0][c] += red[0][c + st];
            red[1][c] += red[1][c + st];
            red[2][c] += red[2][c + st];
        }
        __syncthreads();
    }
    if (c < 3) gv[c] = red[c][0] + db[c];
    __syncthreads();
    float g0 = gv[0], g1 = gv[1], g2 = gv[2];
    for (int h = c; h < 512; h += 256)
        h512[h] = relu(g0 * w3s[h] + g1 * w3s[512 + h] + g2 * w3s[1024 + h] + b3s[h]);
    __syncthreads();
    {
        float acc = 0.f;
        const bf16x8* wr = (const bf16x8*)(w4t + (size_t)c * 512);
        for (int i = 0; i < 64; i++) {
            bf16x8 vv = wr[i];
#pragma unroll
            for (int j = 0; j < 8; j++) acc += h512[i * 8 + j] * bf2f((u16)vv[j]);
        }
        h256[c] = relu(acc + bp4[c]);
    }
    __syncthreads();
    if (c < 128) {
        float acc = 0.f;
        const bf16x8* wr = (const bf16x8*)(w5t + (size_t)c * 256);
        for (int i = 0; i < 32; i++) {
            bf16x8 vv = wr[i];
#pragma unroll
            for (int j = 0; j < 8; j++) acc += h256[i * 8 + j] * bf2f((u16)vv[j]);
        }
        u32 mybits = __float_as_uint(relu(acc + bp5[c]));
        u32 old = atomicMax(&netmax[b * 128 + c], mybits);
        u32 fin = old > mybits ? old : mybits;
        // final bn_globf + store
        float vv = __uint_as_float(fin);
        float gg = bng[c], bee = bng[128 + c], mm = bng[256 + c], va = bng[384 + c];
        float ss = gg * rsqrtf(va + EPSBN);
        float val = vv * ss + (bee - mm * ss);
        int oi = b * 128 + c;
        if (flag[0]) ((u16*)out)[oi] = f2bf(val);
        else ((float*)out)[oi] = val;
    }
}

extern "C" void kernel_launch(void* const* d_in, const int* in_sizes, int n_in,
                              void* d_out, int out_size, void* d_ws, size_t ws_size,
                              hipStream_t stream) {
    float* ws = (float*)d_ws;
    const int* indices = (const int*)d_in[1];

    SmallCv sc;
    {
        static const int srcix[12] = {2, 3, 4, 5, 6, 7, 8, 9, 16, 17, 18, 28};
        static const int nels[12] = {192, 64, 256, 4096, 64, 256, 576, 9, 1024, 768, 3, 512};
        static const int offs[12] = {A_TC1W, A_TC1B, A_TBN1, A_TD1W, A_TD1B, A_TBN2, A_TD2W, A_TD2B,
                                     A_BN3, A_D1W, A_D1B, A_BNGF};
        for (int i = 0; i < 12; i++) { sc.src[i] = d_in[srcix[i]]; sc.n[i] = nels[i]; sc.off[i] = offs[i]; }
    }
    PrepWA pw;
    pw.src[0] = d_in[10]; pw.bn[0] = d_in[12]; pw.K[0] = 96;  pw.logN[0] = 7; pw.base[0] = 0;  pw.dstoff[0] = T_C1WT;
    pw.src[1] = d_in[13]; pw.bn[1] = d_in[15]; pw.K[1] = 128; pw.logN[1] = 8; pw.base[1] = 6;  pw.dstoff[1] = T_C2WT;
    pw.src[2] = d_in[22]; pw.bn[2] = d_in[24]; pw.K[2] = 512; pw.logN[2] = 8; pw.base[2] = 22; pw.dstoff[2] = T_W4T;
    pw.src[3] = d_in[25]; pw.bn[3] = d_in[27]; pw.K[3] = 256; pw.logN[3] = 7; pw.base[3] = 86; pw.dstoff[3] = T_W5T;
    PrepSm ps;
    ps.bn4 = d_in[21]; ps.c3w = d_in[19]; ps.c3b = d_in[20];
    ps.bn2 = d_in[15]; ps.c2b = d_in[14];
    ps.blk1bn = d_in[24]; ps.blk1b = d_in[23];
    ps.bn1 = d_in[12]; ps.c1b = d_in[11];
    ps.blk2bn = d_in[27]; ps.blk2b = d_in[26];

    k_prep<<<140, 256, 0, stream>>>(sc, pw, ps, d_in[0], (const u16*)d_in[4], ws);

    k_tnet<<<32, 256, 0, stream>>>(ws + A_INPUTS, ws + A_TC1W, ws + A_TC1B, ws + A_TBN1,
                                   ws + A_TD1W, ws + A_TD1B, ws + A_TBN2,
                                   ws + A_TD2W, ws + A_TD2B, ws + S_PCT);

    k_featmlp<<<2048, 256, 0, stream>>>(ws + S_PCT, indices,
                                        (const u16*)(ws + T_C1WT), ws + P_BP1,
                                        (const u16*)(ws + T_C2WT), ws + P_BP2,
                                        (u32*)(ws + S_MAXF),
                                        ws + P_W3S, ws + P_B3S,
                                        (const u16*)(ws + T_W4T), ws + P_BP4,
                                        (const u16*)(ws + T_W5T), ws + P_BP5,
                                        (u32*)(ws + S_NETMAX));

    k_gtail<<<32, 256, 0, stream>>>((u32*)(ws + S_MAXF), ws + A_BN3, ws + A_D1W, ws + A_D1B,
                                    ws + P_W3S, ws + P_B3S,
                                    (const u16*)(ws + T_W4T), ws + P_BP4,
                                    (const u16*)(ws + T_W5T), ws + P_BP5,
                                    (u32*)(ws + S_NETMAX),
                                    ws + A_BNGF, (u32*)ws, d_out);
}

// Round 12
// 247.808 us; speedup vs baseline: 1.2812x; 1.0817x over previous
//
#include <hip/hip_runtime.h>

typedef unsigned short u16;
typedef unsigned int u32;
typedef __attribute__((ext_vector_type(8))) short bf16x8;
typedef __attribute__((ext_vector_type(4))) float f32x4;

#define EPSBN 0.001f
#define MFMA16(a, b, c) __builtin_amdgcn_mfma_f32_16x16x32_bf16(a, b, c, 0, 0, 0)

__device__ __forceinline__ float bf2f(u16 u) {
    return __uint_as_float(((u32)u) << 16);
}
__device__ __forceinline__ u16 f2bf(float f) {
    u32 u = __float_as_uint(f);
    u32 r = u + 0x7FFFu + ((u >> 16) & 1u);
    return (u16)(r >> 16);
}
__device__ __forceinline__ float relu(float x) { return x > 0.f ? x : 0.f; }
__device__ __forceinline__ float rdv(const void* p, int i, int isbf) {
    return isbf ? bf2f(((const u16*)p)[i]) : ((const float*)p)[i];
}

// ---------------- ws layout (float offsets) ----------------
// [0]: flag u32
#define A_INPUTS 64       // 196608
#define A_TC1W  196672
#define A_TC1B  196864
#define A_TBN1  196928
#define A_TD1W  197184
#define A_TD1B  201280
#define A_TBN2  201344
#define A_TD2W  201600
#define A_TD2B  202176
#define A_BN3   249216
#define A_D1W   250240
#define A_D1B   251008
#define A_BNGF  420928
#define S_PCT   423808    // 196608 (32*2048*3 f32)
// zeroed region: [S_MAXF, S_MAXF+14336)
#define S_MAXF  620544    // 8192 u32 (maxfeats)
#define S_NETMAX 628736   // 4096 u32
#define S_XMAX  632832    // 2048 u32
// bf16 transposed+scaled weight arenas
#define T_C1WT  634880    // 128x96  u16
#define T_C2WT  641024    // 256x128 u16
#define T_W4T   657408    // 256x512 u16
#define T_W5T   722944    // 128x256 u16
// folded small params (f32)
#define P_W3S   739328    // 1536
#define P_B3S   740864    // 512
#define P_BP1   741376    // 128
#define P_BP2   741504    // 256
#define P_BP4   741760    // 256
#define P_BP5   742016    // 128
// end 742144 floats = 2.97 MB

struct SmallCv { const void* src[12]; int n[12]; int off[12]; };
struct PrepWA { const void* src[4]; const void* bn[4]; int K[4]; int logN[4]; int base[4]; int dstoff[4]; };
struct PrepSm { const void *bn4, *c3w, *c3b, *bn2, *c2b, *blk1bn, *blk1b, *bn1, *c1b, *blk2bn, *blk2b; };

// ================= K0: prep everything (140 blocks) =================
__global__ __launch_bounds__(256) void k_prep(SmallCv sc, PrepWA pw, PrepSm ps,
                                              const void* __restrict__ inputs_raw,
                                              const u16* __restrict__ tbn1_raw,
                                              float* __restrict__ ws) {
    __shared__ float tile[32][65];
    __shared__ float scol[64];
    int isbf = 1;
    for (int i = 0; i < 16; i += 2) {
        u16 v = tbn1_raw[i];
        if (v < 0x3E00u || v > 0x4080u) isbf = 0;
    }
    int bx = blockIdx.x, tid = threadIdx.x;
    if (bx < 32) {
        float* dst = ws + A_INPUTS;
        for (int i = bx * 256 + tid; i < 196608; i += 8192) dst[i] = rdv(inputs_raw, i, isbf);
    } else if (bx < 36) {
        int t0 = (bx - 32) * 3;
        for (int t = t0; t < t0 + 3; t++) {
            int n = sc.n[t];
            float* dst = ws + sc.off[t];
            for (int i = tid; i < n; i += 256) dst[i] = rdv(sc.src[t], i, isbf);
        }
    } else if (bx < 138) {
        int blk = bx - 36;
        int t = (blk < 6) ? 0 : (blk < 22) ? 1 : (blk < 86) ? 2 : 3;
        int tt = blk - pw.base[t];
        int N = 1 << pw.logN[t];
        int K = pw.K[t];
        int ct = N >> 6;
        int k0 = (tt / ct) * 32, c0 = (tt % ct) * 64;
        if (tid < 64) {
            int c = c0 + tid;
            scol[tid] = rdv(pw.bn[t], c, isbf) * rsqrtf(rdv(pw.bn[t], 3 * N + c, isbf) + EPSBN);
        }
        __syncthreads();
#pragma unroll
        for (int pr = 0; pr < 8; pr++) {
            int kr = pr * 4 + (tid >> 6), cc = tid & 63;
            tile[kr][cc] = rdv(pw.src[t], (k0 + kr) * N + c0 + cc, isbf) * scol[cc];
        }
        __syncthreads();
        u32* d32 = (u32*)((u16*)(ws + pw.dstoff[t]));
#pragma unroll
        for (int pw2 = 0; pw2 < 4; pw2++) {
            int cr = pw2 * 16 + (tid >> 4);
            int kp = tid & 15;
            u32 pk = (u32)f2bf(tile[kp * 2][cr]) | ((u32)f2bf(tile[kp * 2 + 1][cr]) << 16);
            d32[(((c0 + cr) * K + k0) >> 1) + kp] = pk;
        }
    } else if (bx == 138) {
        for (int c = tid; c < 512; c += 256) {
            float s = rdv(ps.bn4, c, isbf) * rsqrtf(rdv(ps.bn4, 1536 + c, isbf) + EPSBN);
            float t = rdv(ps.bn4, 512 + c, isbf) - rdv(ps.bn4, 1024 + c, isbf) * s;
            ws[P_W3S + c]        = rdv(ps.c3w, c, isbf) * s;
            ws[P_W3S + 512 + c]  = rdv(ps.c3w, 512 + c, isbf) * s;
            ws[P_W3S + 1024 + c] = rdv(ps.c3w, 1024 + c, isbf) * s;
            ws[P_B3S + c] = rdv(ps.c3b, c, isbf) * s + t;
        }
        {
            int c = tid;
            float s2 = rdv(ps.bn2, c, isbf) * rsqrtf(rdv(ps.bn2, 768 + c, isbf) + EPSBN);
            ws[P_BP2 + c] = rdv(ps.c2b, c, isbf) * s2 + (rdv(ps.bn2, 256 + c, isbf) - rdv(ps.bn2, 512 + c, isbf) * s2);
            float s5 = rdv(ps.blk1bn, c, isbf) * rsqrtf(rdv(ps.blk1bn, 768 + c, isbf) + EPSBN);
            ws[P_BP4 + c] = rdv(ps.blk1b, c, isbf) * s5 + (rdv(ps.blk1bn, 256 + c, isbf) - rdv(ps.blk1bn, 512 + c, isbf) * s5);
        }
        if (tid < 128) {
            int c = tid;
            float s1 = rdv(ps.bn1, c, isbf) * rsqrtf(rdv(ps.bn1, 384 + c, isbf) + EPSBN);
            ws[P_BP1 + c] = rdv(ps.c1b, c, isbf) * s1 + (rdv(ps.bn1, 128 + c, isbf) - rdv(ps.bn1, 256 + c, isbf) * s1);
            float s6 = rdv(ps.blk2bn, c, isbf) * rsqrtf(rdv(ps.blk2bn, 384 + c, isbf) + EPSBN);
            ws[P_BP5 + c] = rdv(ps.blk2b, c, isbf) * s6 + (rdv(ps.blk2bn, 128 + c, isbf) - rdv(ps.blk2bn, 256 + c, isbf) * s6);
        }
    } else {
        u32* z = (u32*)(ws + S_MAXF);
        for (int i = tid; i < 14336; i += 256) z[i] = 0u;
        if (tid == 0) ((u32*)ws)[0] = (u32)isbf;
    }
}

// ================= K1a: t-net stage 1, 8 slices x 32 batches =================
__global__ __launch_bounds__(256) void k_tnet1(const float* __restrict__ inp,
                                               const float* __restrict__ w,
                                               const float* __restrict__ bias,
                                               const float* __restrict__ bn,
                                               u32* __restrict__ xmax) {
    __shared__ float pts[768];     // 256 points x 3
    __shared__ float wred[4][64];
    int b = blockIdx.y, slice = blockIdx.x, tid = threadIdx.x;
    const float* ip = inp + ((size_t)b * 2048 + slice * 256) * 3;
    pts[tid] = ip[tid];
    pts[tid + 256] = ip[tid + 256];
    pts[tid + 512] = ip[tid + 512];

    int c = tid & 63, np = tid >> 6;
    float w0 = w[c], w1c = w[64 + c], w2c = w[128 + c], bi = bias[c];
    float g = bn[c], be = bn[64 + c], m = bn[128 + c], v = bn[192 + c];
    float s = g * rsqrtf(v + EPSBN), t = be - m * s;
    __syncthreads();

    float vmax = -1e30f;
    int pbase = np * 64;
#pragma unroll 4
    for (int p = 0; p < 64; p++) {
        float x0 = pts[(pbase + p) * 3], x1 = pts[(pbase + p) * 3 + 1], x2 = pts[(pbase + p) * 3 + 2];
        float z = x0 * w0 + x1 * w1c + x2 * w2c + bi;
        vmax = fmaxf(vmax, z * s + t);
    }
    wred[np][c] = vmax;
    __syncthreads();
    if (tid < 64) {
        float mm = fmaxf(fmaxf(wred[0][tid], wred[1][tid]), fmaxf(wred[2][tid], wred[3][tid]));
        atomicMax(&xmax[b * 64 + tid], __float_as_uint(relu(mm)));
    }
}

// ================= K1b: t-net stage 2 + transform + pct (32 blocks) =================
__global__ __launch_bounds__(256) void k_tnet2pct(const float* __restrict__ inp,
                                                  const u32* __restrict__ xmax,
                                                  const float* __restrict__ w1, const float* __restrict__ b1,
                                                  const float* __restrict__ bn2p,
                                                  const float* __restrict__ w2, const float* __restrict__ b2,
                                                  float* __restrict__ pct) {
    __shared__ float x1v[64];
    __shared__ float x2v[64];
    __shared__ float tf[9];
    int b = blockIdx.x, tid = threadIdx.x;
    if (tid < 64) x1v[tid] = __uint_as_float(xmax[b * 64 + tid]);  // already relu'd
    __syncthreads();
    if (tid < 64) {
        float acc = b1[tid];
        for (int j = 0; j < 64; j++) acc += x1v[j] * w1[j * 64 + tid];
        float g2 = bn2p[tid], be2 = bn2p[64 + tid], m2 = bn2p[128 + tid], v2 = bn2p[192 + tid];
        float s2 = g2 * rsqrtf(v2 + EPSBN);
        x2v[tid] = relu(acc * s2 + (be2 - m2 * s2));
    }
    __syncthreads();
    if (tid < 9) {
        float a = b2[tid];
        for (int j = 0; j < 64; j++) a += x2v[j] * w2[j * 9 + tid];
        tf[tid] = a;
    }
    __syncthreads();
    float t0 = tf[0], t1 = tf[1], t2 = tf[2], t3 = tf[3], t4 = tf[4];
    float t5 = tf[5], t6 = tf[6], t7 = tf[7], t8 = tf[8];
    const float* ip = inp + (size_t)b * 2048 * 3;
    float* op = pct + (size_t)b * 2048 * 3;
#pragma unroll
    for (int i = 0; i < 8; i++) {
        int p = tid + i * 256;
        float x0 = ip[p * 3], x1 = ip[p * 3 + 1], x2 = ip[p * 3 + 2];
        op[p * 3]     = x0 * t0 + x1 * t3 + x2 * t6;
        op[p * 3 + 1] = x0 * t1 + x1 * t4 + x2 * t7;
        op[p * 3 + 2] = x0 * t2 + x1 * t5 + x2 * t8;
    }
}

// ================= K2: fused feat/mlp, 35KB LDS, XCD swizzle, B-prefetch pipeline =================
__global__ __launch_bounds__(256, 3) void k_featmlp(
    const float* __restrict__ pct, const int* __restrict__ indices,
    const u16* __restrict__ w1t, const float* __restrict__ bp1,
    const u16* __restrict__ w2t, const float* __restrict__ bp2,
    u32* __restrict__ maxfeats,
    const float* __restrict__ w3s, const float* __restrict__ b3s,
    const u16* __restrict__ w4t, const float* __restrict__ bp4,
    const u16* __restrict__ w5t, const float* __restrict__ bp5,
    u32* __restrict__ netmax) {
    __shared__ __align__(16) char SM[35328];
    int bx0 = blockIdx.x, tid = threadIdx.x;
    // XCD-chunked swizzle: each XCD (bx0%8) owns a contiguous 256-block chunk = 4 batches.
    int bx = ((bx0 & 7) << 8) + (bx0 >> 3);
    int part = bx & 1;
    int idx = bx >> 1;
    int b = idx >> 5, sub = idx & 31;
    int lane = tid & 63, wv = tid >> 6;
    int rw = lane & 15, kq = lane >> 4;
    int axor = (rw & 7) << 4;

    if (part == 0) {
        // ---------------- feat: gather -> 96->128 -> 128->256 -> channel max ----------------
        char* ftA = SM;                       // [64][128] u16 pitch 256B swizzled (96 used)
        char* h1B = SM + 16384;               // [64][128] u16 pitch 256B swizzled
        float* sp1 = (float*)(SM + 32768);    // 128
        float* sp2 = (float*)(SM + 33280);    // 256
        int n0p = sub * 64;
        sp2[tid] = bp2[tid];
        if (tid < 128) sp1[tid] = bp1[tid];
        {
            const float* pb = pct + (size_t)b * 2048 * 3;
            const int* ib = indices + ((size_t)b * 2048 + n0p) * 32;
#pragma unroll
            for (int r = 0; r < 8; r++) {
                int i = tid + 256 * r;
                int p = i >> 5, k = i & 31;
                int idxp = ib[p * 32 + k];
                const float* s = pb + (size_t)idxp * 3;
                int sw = (p & 7) << 4;
                int base = p * 256 + 6 * k;
                *(u16*)(ftA + ((base) ^ sw))     = f2bf(s[0]);
                *(u16*)(ftA + ((base + 2) ^ sw)) = f2bf(s[1]);
                *(u16*)(ftA + ((base + 4) ^ sw)) = f2bf(s[2]);
            }
        }
        __syncthreads();
        // GEMM A: [64][96] x W1T[128][96]
        {
            f32x4 acc[4][2];
#pragma unroll
            for (int m = 0; m < 4; m++)
#pragma unroll
                for (int n = 0; n < 2; n++) acc[m][n] = (f32x4){0.f, 0.f, 0.f, 0.f};
            const char* W = (const char*)w1t;
            int nb = wv * 32;
#pragma unroll
            for (int ks = 0; ks < 3; ks++) {
                int kb = ks * 64 + kq * 16;
                bf16x8 b0 = *(const bf16x8*)(W + (nb + rw) * 192 + kb);
                bf16x8 b1 = *(const bf16x8*)(W + (nb + 16 + rw) * 192 + kb);
                bf16x8 a0 = *(const bf16x8*)(ftA + (((rw) * 256 + kb) ^ axor));
                bf16x8 a1 = *(const bf16x8*)(ftA + (((rw + 16) * 256 + kb) ^ axor));
                bf16x8 a2 = *(const bf16x8*)(ftA + (((rw + 32) * 256 + kb) ^ axor));
                bf16x8 a3 = *(const bf16x8*)(ftA + (((rw + 48) * 256 + kb) ^ axor));
                acc[0][0] = MFMA16(a0, b0, acc[0][0]); acc[0][1] = MFMA16(a0, b1, acc[0][1]);
                acc[1][0] = MFMA16(a1, b0, acc[1][0]); acc[1][1] = MFMA16(a1, b1, acc[1][1]);
                acc[2][0] = MFMA16(a2, b0, acc[2][0]); acc[2][1] = MFMA16(a2, b1, acc[2][1]);
                acc[3][0] = MFMA16(a3, b0, acc[3][0]); acc[3][1] = MFMA16(a3, b1, acc[3][1]);
            }
#pragma unroll
            for (int nt = 0; nt < 2; nt++) {
                int c = nb + nt * 16 + rw;
                float bb = sp1[c];
#pragma unroll
                for (int m = 0; m < 4; m++)
#pragma unroll
                    for (int r = 0; r < 4; r++) {
                        int rr = m * 16 + kq * 4 + r;
                        float h = relu(acc[m][nt][r] + bb);
                        *(u16*)(h1B + ((rr * 256 + c * 2) ^ ((rr & 7) << 4))) = f2bf(h);
                    }
            }
        }
        __syncthreads();
        // GEMM B: [64][128] x W2T[256][128] -> channel max, B prefetched 1 ks ahead
        {
            f32x4 acc[4][4];
#pragma unroll
            for (int m = 0; m < 4; m++)
#pragma unroll
                for (int n = 0; n < 4; n++) acc[m][n] = (f32x4){0.f, 0.f, 0.f, 0.f};
            const char* W = (const char*)w2t;
            int nb = wv * 64;
            bf16x8 p0 = *(const bf16x8*)(W + (nb + rw) * 256 + kq * 16);
            bf16x8 p1 = *(const bf16x8*)(W + (nb + 16 + rw) * 256 + kq * 16);
            bf16x8 p2 = *(const bf16x8*)(W + (nb + 32 + rw) * 256 + kq * 16);
            bf16x8 p3 = *(const bf16x8*)(W + (nb + 48 + rw) * 256 + kq * 16);
#pragma unroll
            for (int ks = 0; ks < 4; ks++) {
                int kb = ks * 64 + kq * 16;
                bf16x8 a0 = *(const bf16x8*)(h1B + (((rw) * 256 + kb) ^ axor));
                bf16x8 a1 = *(const bf16x8*)(h1B + (((rw + 16) * 256 + kb) ^ axor));
                bf16x8 a2 = *(const bf16x8*)(h1B + (((rw + 32) * 256 + kb) ^ axor));
                bf16x8 a3 = *(const bf16x8*)(h1B + (((rw + 48) * 256 + kb) ^ axor));
                bf16x8 b0 = p0, b1 = p1, b2 = p2, b3 = p3;
                if (ks < 3) {
                    int kn = (ks + 1) * 64 + kq * 16;
                    p0 = *(const bf16x8*)(W + (nb + rw) * 256 + kn);
                    p1 = *(const bf16x8*)(W + (nb + 16 + rw) * 256 + kn);
                    p2 = *(const bf16x8*)(W + (nb + 32 + rw) * 256 + kn);
                    p3 = *(const bf16x8*)(W + (nb + 48 + rw) * 256 + kn);
                }
                acc[0][0] = MFMA16(a0, b0, acc[0][0]); acc[1][0] = MFMA16(a1, b0, acc[1][0]);
                acc[2][0] = MFMA16(a2, b0, acc[2][0]); acc[3][0] = MFMA16(a3, b0, acc[3][0]);
                acc[0][1] = MFMA16(a0, b1, acc[0][1]); acc[1][1] = MFMA16(a1, b1, acc[1][1]);
                acc[2][1] = MFMA16(a2, b1, acc[2][1]); acc[3][1] = MFMA16(a3, b1, acc[3][1]);
                acc[0][2] = MFMA16(a0, b2, acc[0][2]); acc[1][2] = MFMA16(a1, b2, acc[1][2]);
                acc[2][2] = MFMA16(a2, b2, acc[2][2]); acc[3][2] = MFMA16(a3, b2, acc[3][2]);
                acc[0][3] = MFMA16(a0, b3, acc[0][3]); acc[1][3] = MFMA16(a1, b3, acc[1][3]);
                acc[2][3] = MFMA16(a2, b3, acc[2][3]); acc[3][3] = MFMA16(a3, b3, acc[3][3]);
            }
#pragma unroll
            for (int nt = 0; nt < 4; nt++) {
                int c = nb + nt * 16 + rw;
                float bb = sp2[c];
                float vm = 0.f;
#pragma unroll
                for (int m = 0; m < 4; m++)
#pragma unroll
                    for (int r = 0; r < 4; r++)
                        vm = fmaxf(vm, relu(acc[m][nt][r] + bb));
                vm = fmaxf(vm, __shfl_xor(vm, 16));
                vm = fmaxf(vm, __shfl_xor(vm, 32));
                if (kq == 0) atomicMax(&maxfeats[b * 256 + c], __float_as_uint(vm));
            }
        }
    } else {
        // ---------------- mlp-main: rows sub*64.., 3->512->256->128 + row max ----------------
        char* hA0 = SM;                       // [64][64] u16 pitch 128B swizzled
        char* hA1 = SM + 8192;
        char* HB  = SM + 16384;               // [32][256] u16 pitch 512B swizzled (half rows)
        float* rows4 = (float*)(SM + 32768);  // [64][4]
        float* sb4 = (float*)(SM + 33792);    // 256
        float* sb5 = (float*)(SM + 34816);    // 128
        int r0 = sub * 64;

        sb4[tid] = bp4[tid];
        if (tid < 128) sb5[tid] = bp5[tid];
        if (tid < 64) {
            const float* s = pct + ((size_t)b * 2048 + r0 + tid) * 3;
            rows4[tid * 4] = s[0]; rows4[tid * 4 + 1] = s[1]; rows4[tid * 4 + 2] = s[2];
        }
        __syncthreads();

        auto phase1 = [&](int c, char* dst) {
            int c2 = (tid & 31) * 2;
            int rg = tid >> 5;
            int ch = c * 64 + c2;
            float wa0 = w3s[ch], wa1 = w3s[512 + ch], wa2 = w3s[1024 + ch], ba = b3s[ch];
            float wb0 = w3s[ch + 1], wb1 = w3s[513 + ch], wb2 = w3s[1025 + ch], bb2 = b3s[ch + 1];
#pragma unroll
            for (int r = 0; r < 8; r++) {
                int row = rg * 8 + r;
                float x0 = rows4[row * 4], x1 = rows4[row * 4 + 1], x2 = rows4[row * 4 + 2];
                float ha = relu(x0 * wa0 + x1 * wa1 + x2 * wa2 + ba);
                float hb = relu(x0 * wb0 + x1 * wb1 + x2 * wb2 + bb2);
                u32 pk = (u32)f2bf(ha) | ((u32)f2bf(hb) << 16);
                *(u32*)(dst + ((row * 128 + c2 * 2) ^ ((row & 7) << 4))) = pk;
            }
        };

        phase1(0, hA0);
        __syncthreads();

        // phase 2: [64][512] x W4T[256][512] -> acc, B prefetched 1 chunk ahead (ksl0 half)
        f32x4 acc[4][4];
#pragma unroll
        for (int m = 0; m < 4; m++)
#pragma unroll
            for (int n = 0; n < 4; n++) acc[m][n] = (f32x4){0.f, 0.f, 0.f, 0.f};
        {
            const char* W = (const char*)w4t;
            int nb = wv * 64;
            auto ldB = [&](int c, int ksl, int nt) -> bf16x8 {
                return *(const bf16x8*)(W + (nb + nt * 16 + rw) * 1024 + c * 128 + ksl * 64 + kq * 16);
            };
            bf16x8 pf0 = ldB(0, 0, 0), pf1 = ldB(0, 0, 1), pf2 = ldB(0, 0, 2), pf3 = ldB(0, 0, 3);
            for (int c = 0; c < 8; c++) {
                bf16x8 q0 = ldB(c, 1, 0), q1 = ldB(c, 1, 1), q2 = ldB(c, 1, 2), q3 = ldB(c, 1, 3);
                if (c < 7) phase1(c + 1, (c & 1) ? hA0 : hA1);
                const char* A = (c & 1) ? hA1 : hA0;
                // ksl 0 with prefetched pf*
                {
                    int kb = kq * 16;
                    bf16x8 a0 = *(const bf16x8*)(A + (((rw) * 128 + kb) ^ axor));
                    bf16x8 a1 = *(const bf16x8*)(A + (((rw + 16) * 128 + kb) ^ axor));
                    bf16x8 a2 = *(const bf16x8*)(A + (((rw + 32) * 128 + kb) ^ axor));
                    bf16x8 a3 = *(const bf16x8*)(A + (((rw + 48) * 128 + kb) ^ axor));
                    acc[0][0] = MFMA16(a0, pf0, acc[0][0]); acc[1][0] = MFMA16(a1, pf0, acc[1][0]);
                    acc[2][0] = MFMA16(a2, pf0, acc[2][0]); acc[3][0] = MFMA16(a3, pf0, acc[3][0]);
                    acc[0][1] = MFMA16(a0, pf1, acc[0][1]); acc[1][1] = MFMA16(a1, pf1, acc[1][1]);
                    acc[2][1] = MFMA16(a2, pf1, acc[2][1]); acc[3][1] = MFMA16(a3, pf1, acc[3][1]);
                    acc[0][2] = MFMA16(a0, pf2, acc[0][2]); acc[1][2] = MFMA16(a1, pf2, acc[1][2]);
                    acc[2][2] = MFMA16(a2, pf2, acc[2][2]); acc[3][2] = MFMA16(a3, pf2, acc[3][2]);
                    acc[0][3] = MFMA16(a0, pf3, acc[0][3]); acc[1][3] = MFMA16(a1, pf3, acc[1][3]);
                    acc[2][3] = MFMA16(a2, pf3, acc[2][3]); acc[3][3] = MFMA16(a3, pf3, acc[3][3]);
                }
                if (c < 7) { pf0 = ldB(c + 1, 0, 0); pf1 = ldB(c + 1, 0, 1); pf2 = ldB(c + 1, 0, 2); pf3 = ldB(c + 1, 0, 3); }
                // ksl 1 with q* (covered by phase1 + ksl0 MFMA block)
                {
                    int kb = 64 + kq * 16;
                    bf16x8 a0 = *(const bf16x8*)(A + (((rw) * 128 + kb) ^ axor));
                    bf16x8 a1 = *(const bf16x8*)(A + (((rw + 16) * 128 + kb) ^ axor));
                    bf16x8 a2 = *(const bf16x8*)(A + (((rw + 32) * 128 + kb) ^ axor));
                    bf16x8 a3 = *(const bf16x8*)(A + (((rw + 48) * 128 + kb) ^ axor));
                    acc[0][0] = MFMA16(a0, q0, acc[0][0]); acc[1][0] = MFMA16(a1, q0, acc[1][0]);
                    acc[2][0] = MFMA16(a2, q0, acc[2][0]); acc[3][0] = MFMA16(a3, q0, acc[3][0]);
                    acc[0][1] = MFMA16(a0, q1, acc[0][1]); acc[1][1] = MFMA16(a1, q1, acc[1][1]);
                    acc[2][1] = MFMA16(a2, q1, acc[2][1]); acc[3][1] = MFMA16(a3, q1, acc[3][1]);
                    acc[0][2] = MFMA16(a0, q2, acc[0][2]); acc[1][2] = MFMA16(a1, q2, acc[1][2]);
                    acc[2][2] = MFMA16(a2, q2, acc[2][2]); acc[3][2] = MFMA16(a3, q2, acc[3][2]);
                    acc[0][3] = MFMA16(a0, q3, acc[0][3]); acc[1][3] = MFMA16(a1, q3, acc[1][3]);
                    acc[2][3] = MFMA16(a2, q3, acc[2][3]); acc[3][3] = MFMA16(a3, q3, acc[3][3]);
                }
                __syncthreads();
            }
        }
        // epilogue + phase 3 in two 32-row halves, W5 prefetched 1 ks ahead
        float vm[2] = {0.f, 0.f};
        const char* W5 = (const char*)w5t;
        int nb2 = wv * 32;
#pragma unroll
        for (int h = 0; h < 2; h++) {
#pragma unroll
            for (int nt = 0; nt < 4; nt++) {
                int c = wv * 64 + nt * 16 + rw;
                float bb = sb4[c];
#pragma unroll
                for (int m = 0; m < 2; m++) {
                    int mm = h * 2 + m;
#pragma unroll
                    for (int r = 0; r < 4; r++) {
                        int rr = m * 16 + kq * 4 + r;   // local row 0..31
                        float hh = relu(acc[mm][nt][r] + bb);
                        *(u16*)(HB + ((rr * 512 + c * 2) ^ ((rr & 7) << 4))) = f2bf(hh);
                    }
                }
            }
            __syncthreads();
            f32x4 acc3[2][2];
#pragma unroll
            for (int m = 0; m < 2; m++)
#pragma unroll
                for (int n = 0; n < 2; n++) acc3[m][n] = (f32x4){0.f, 0.f, 0.f, 0.f};
            bf16x8 pb0 = *(const bf16x8*)(W5 + (nb2 + rw) * 512 + kq * 16);
            bf16x8 pb1 = *(const bf16x8*)(W5 + (nb2 + 16 + rw) * 512 + kq * 16);
#pragma unroll
            for (int ks = 0; ks < 8; ks++) {
                int kb = ks * 64 + kq * 16;
                bf16x8 b0 = pb0, b1 = pb1;
                bf16x8 a0 = *(const bf16x8*)(HB + (((rw) * 512 + kb) ^ axor));
                bf16x8 a1 = *(const bf16x8*)(HB + (((rw + 16) * 512 + kb) ^ axor));
                if (ks < 7) {
                    int kn = (ks + 1) * 64 + kq * 16;
                    pb0 = *(const bf16x8*)(W5 + (nb2 + rw) * 512 + kn);
                    pb1 = *(const bf16x8*)(W5 + (nb2 + 16 + rw) * 512 + kn);
                }
                acc3[0][0] = MFMA16(a0, b0, acc3[0][0]); acc3[0][1] = MFMA16(a0, b1, acc3[0][1]);
                acc3[1][0] = MFMA16(a1, b0, acc3[1][0]); acc3[1][1] = MFMA16(a1, b1, acc3[1][1]);
            }
#pragma unroll
            for (int nt = 0; nt < 2; nt++) {
                int c = nb2 + nt * 16 + rw;
                float bb = sb5[c];
#pragma unroll
                for (int m = 0; m < 2; m++)
#pragma unroll
                    for (int r = 0; r < 4; r++)
                        vm[nt] = fmaxf(vm[nt], relu(acc3[m][nt][r] + bb));
            }
            __syncthreads();
        }
#pragma unroll
        for (int nt = 0; nt < 2; nt++) {
            int c = nb2 + nt * 16 + rw;
            float v = vm[nt];
            v = fmaxf(v, __shfl_xor(v, 16));
            v = fmaxf(v, __shfl_xor(v, 32));
            if (kq == 0) atomicMax(&netmax[b * 128 + c], __float_as_uint(v));
        }
    }
}

// ================= K3: g-row tail + final bn/out =================
__global__ __launch_bounds__(256) void k_gtail(const u32* __restrict__ maxfeats,
                                               const float* __restrict__ bn3p,
                                               const float* __restrict__ dw, const float* __restrict__ db,
                                               const float* __restrict__ w3s, const float* __restrict__ b3s,
                                               const u16* __restrict__ w4t, const float* __restrict__ bp4,
                                               const u16* __restrict__ w5t, const float* __restrict__ bp5,
                                               u32* __restrict__ netmax,
                                               const float* __restrict__ bng,
                                               const u32* __restrict__ flag,
                                               void* __restrict__ out) {
    __shared__ float red[3][256];
    __shared__ float h512[512];
    __shared__ float h256[256];
    __shared__ float gv[4];
    int b = blockIdx.x, c = threadIdx.x;
    float mf = __uint_as_float(maxfeats[b * 256 + c]);
    float g = bn3p[c], be = bn3p[256 + c], m = bn3p[512 + c], v = bn3p[768 + c];
    float s = g * rsqrtf(v + EPSBN);
    float y = mf * s + (be - m * s);  // no relu on bn3
    red[0][c] = y * dw[c * 3 + 0];
    red[1][c] = y * dw[c * 3 + 1];
    red[2][c] = y * dw[c * 3 + 2];
    __syncthreads();
    for (int st = 128; st > 0; st >>= 1) {
        if (c < st) {
            red[0][c] += red[0][c + st];
            red[1][c] += red[1][c + st];
            red[2][c] += red[2][c + st];
        }
        __syncthreads();
    }
    if (c < 3) gv[c] = red[c][0] + db[c];
    __syncthreads();
    float g0 = gv[0], g1 = gv[1], g2 = gv[2];
    for (int h = c; h < 512; h += 256)
        h512[h] = relu(g0 * w3s[h] + g1 * w3s[512 + h] + g2 * w3s[1024 + h] + b3s[h]);
    __syncthreads();
    {
        float acc = 0.f;
        const bf16x8* wr = (const bf16x8*)(w4t + (size_t)c * 512);
        for (int i = 0; i < 64; i++) {
            bf16x8 vv = wr[i];
#pragma unroll
            for (int j = 0; j < 8; j++) acc += h512[i * 8 + j] * bf2f((u16)vv[j]);
        }
        h256[c] = relu(acc + bp4[c]);
    }
    __syncthreads();
    if (c < 128) {
        float acc = 0.f;
        const bf16x8* wr = (const bf16x8*)(w5t + (size_t)c * 256);
        for (int i = 0; i < 32; i++) {
            bf16x8 vv = wr[i];
#pragma unroll
            for (int j = 0; j < 8; j++) acc += h256[i * 8 + j] * bf2f((u16)vv[j]);
        }
        u32 mybits = __float_as_uint(relu(acc + bp5[c]));
        u32 old = atomicMax(&netmax[b * 128 + c], mybits);
        u32 fin = old > mybits ? old : mybits;
        float vv = __uint_as_float(fin);
        float gg = bng[c], bee = bng[128 + c], mm = bng[256 + c], va = bng[384 + c];
        float ss = gg * rsqrtf(va + EPSBN);
        float val = vv * ss + (bee - mm * ss);
        int oi = b * 128 + c;
        if (flag[0]) ((u16*)out)[oi] = f2bf(val);
        else ((float*)out)[oi] = val;
    }
}

extern "C" void kernel_launch(void* const* d_in, const int* in_sizes, int n_in,
                              void* d_out, int out_size, void* d_ws, size_t ws_size,
                              hipStream_t stream) {
    float* ws = (float*)d_ws;
    const int* indices = (const int*)d_in[1];

    SmallCv sc;
    {
        static const int srcix[12] = {2, 3, 4, 5, 6, 7, 8, 9, 16, 17, 18, 28};
        static const int nels[12] = {192, 64, 256, 4096, 64, 256, 576, 9, 1024, 768, 3, 512};
        static const int offs[12] = {A_TC1W, A_TC1B, A_TBN1, A_TD1W, A_TD1B, A_TBN2, A_TD2W, A_TD2B,
                                     A_BN3, A_D1W, A_D1B, A_BNGF};
        for (int i = 0; i < 12; i++) { sc.src[i] = d_in[srcix[i]]; sc.n[i] = nels[i]; sc.off[i] = offs[i]; }
    }
    PrepWA pw;
    pw.src[0] = d_in[10]; pw.bn[0] = d_in[12]; pw.K[0] = 96;  pw.logN[0] = 7; pw.base[0] = 0;  pw.dstoff[0] = T_C1WT;
    pw.src[1] = d_in[13]; pw.bn[1] = d_in[15]; pw.K[1] = 128; pw.logN[1] = 8; pw.base[1] = 6;  pw.dstoff[1] = T_C2WT;
    pw.src[2] = d_in[22]; pw.bn[2] = d_in[24]; pw.K[2] = 512; pw.logN[2] = 8; pw.base[2] = 22; pw.dstoff[2] = T_W4T;
    pw.src[3] = d_in[25]; pw.bn[3] = d_in[27]; pw.K[3] = 256; pw.logN[3] = 7; pw.base[3] = 86; pw.dstoff[3] = T_W5T;
    PrepSm ps;
    ps.bn4 = d_in[21]; ps.c3w = d_in[19]; ps.c3b = d_in[20];
    ps.bn2 = d_in[15]; ps.c2b = d_in[14];
    ps.blk1bn = d_in[24]; ps.blk1b = d_in[23];
    ps.bn1 = d_in[12]; ps.c1b = d_in[11];
    ps.blk2bn = d_in[27]; ps.blk2b = d_in[26];

    k_prep<<<140, 256, 0, stream>>>(sc, pw, ps, d_in[0], (const u16*)d_in[4], ws);

    k_tnet1<<<dim3(8, 32), 256, 0, stream>>>(ws + A_INPUTS, ws + A_TC1W, ws + A_TC1B, ws + A_TBN1,
                                             (u32*)(ws + S_XMAX));
    k_tnet2pct<<<32, 256, 0, stream>>>(ws + A_INPUTS, (const u32*)(ws + S_XMAX),
                                       ws + A_TD1W, ws + A_TD1B, ws + A_TBN2,
                                       ws + A_TD2W, ws + A_TD2B, ws + S_PCT);

    k_featmlp<<<2048, 256, 0, stream>>>(ws + S_PCT, indices,
                                        (const u16*)(ws + T_C1WT), ws + P_BP1,
                                        (const u16*)(ws + T_C2WT), ws + P_BP2,
                                        (u32*)(ws + S_MAXF),
                                        ws + P_W3S, ws + P_B3S,
                                        (const u16*)(ws + T_W4T), ws + P_BP4,
                                        (const u16*)(ws + T_W5T), ws + P_BP5,
                                        (u32*)(ws + S_NETMAX));

    k_gtail<<<32, 256, 0, stream>>>((u32*)(ws + S_MAXF), ws + A_BN3, ws + A_D1W, ws + A_D1B,
                                    ws + P_W3S, ws + P_B3S,
                                    (const u16*)(ws + T_W4T), ws + P_BP4,
                                    (const u16*)(ws + T_W5T), ws + P_BP5,
                                    (u32*)(ws + S_NETMAX),
                                    ws + A_BNGF, (u32*)ws, d_out);
}